// Round 5
// baseline (155.289 us; speedup 1.0000x reference)
//
#include <hip/hip_runtime.h>
#include <hip/hip_cooperative_groups.h>
#include <math.h>

// ---------------------------------------------------------------------------
// PolyNetFP4Sim: out = f(x), scalar->scalar 4-layer SiLU MLP (1->64->64->32->1)
// with fake-FP4 (1-2-1) weights. f is tabulated on 4096 cells over
// [-6.75,6.75] then lerped (tails extrapolate linearly; silu is asymptotically
// linear, so extrapolation is exact in the limit).
// Round 5: cooperative single-kernel probe, launch-legal this time:
//   - 512 blocks (2/CU; fits the runtime's coop occupancy check even under a
//     64KB-shared/CU assumption with our 25.4KB LDS). R4's 1024 blocks was
//     rejected as CooperativeLaunchTooLarge and silently dropped.
//   - hipLaunchCooperativeKernel return code CHECKED; on error fall back to
//     the known-good 3-kernel path (identical math) in the same call.
// ---------------------------------------------------------------------------

namespace cg = cooperative_groups;

#define FAST_RCP(x) __builtin_amdgcn_rcpf(x)

#define N_CELLS 4096
#define N_PTS   (N_CELLS + 1)
#define F_LO    (-6.75f)
#define F_HI    (6.75f)
#define F_H     ((F_HI - F_LO) / (float)N_CELLS)
#define F_INVH  ((float)N_CELLS / (F_HI - F_LO))

#define COOP_BLOCKS 512           /* 2 blocks/CU on 256 CUs */
#define COOP_WAVES  (COOP_BLOCKS * 4)

// Coop-kernel LDS layout (floats): phase-1 weights, reused for phase-2 table.
#define SW2_OFF 0                 /* 64 rows x 65 (padded) = 4160 */
#define SW3_OFF 4160              /* 32 rows x 65 (padded) = 2080 */
#define SW1_OFF 6240              /* 64 */
#define SW4_OFF 6304              /* 32 -> 6336 total */
#define S_MEM_FLOATS 6340         /* >= max(6336, 4100) */

// Workspace layout (floats) for the fallback path.
#define QW1_OFF  0
#define QW2T_OFF 64
#define QW3T_OFF (64 + 4096)
#define QW4_OFF  (64 + 4096 + 2048)
#define TAB_OFF  (64 + 4096 + 2048 + 32)   /* 6240; coop path also puts table here */

__device__ __forceinline__ float quant_fp4(float w) {
    unsigned bits  = __float_as_uint(w);
    unsigned abits = bits & 0x7fffffffu;
    if (abits == 0u) return 0.0f;                  // ±0 -> 0
    int e  = (int)(abits >> 23) - 126;             // frexp: m in [0.5,1)
    int qe = e + 1;
    qe = qe < 0 ? 0 : (qe > 3 ? 3 : qe);
    float base  = (abits & 0x00400000u) ? 0.75f : 0.5f;   // m >= 0.75 ?
    float scale = (qe == 0) ? 0.5f : (qe == 1) ? 1.0f : (qe == 2) ? 2.0f : 4.0f;
    float val = base * scale;
    return (bits & 0x80000000u) ? -val : val;
}

__device__ __forceinline__ float silu(float a) {
    return a * FAST_RCP(1.0f + __expf(-a));
}

__device__ __forceinline__ float rdlane(float v, int i) {
    return __uint_as_float((unsigned)__builtin_amdgcn_readlane((int)__float_as_uint(v), i));
}

__device__ __forceinline__ float lerp1(float xc, const float* s_tab) {
    float tt = fmaf(xc, F_INVH, 2048.0f);          // -F_LO*F_INVH == 2048 exact
    int i = (int)tt;
    i = i < 0 ? 0 : (i > N_CELLS - 1 ? N_CELLS - 1 : i);
    float fr = tt - (float)i;                      // <0 / >1 => extrapolation
    float f0 = s_tab[i];
    float f1 = s_tab[i + 1];
    return fmaf(fr, f1 - f0, f0);
}

// ============================ cooperative path =============================
__global__ __launch_bounds__(256, 2) void fused_kernel(
        const float* __restrict__ x_in,
        const float* __restrict__ w1, const float* __restrict__ b1,
        const float* __restrict__ w2, const float* __restrict__ b2,
        const float* __restrict__ w3, const float* __restrict__ b3,
        const float* __restrict__ w4, const float* __restrict__ b4,
        float* __restrict__ table, float* __restrict__ out, int n) {
    __shared__ float s_mem[S_MEM_FLOATS];
    cg::grid_group grid = cg::this_grid();
    int t = threadIdx.x;

    // ---- Phase 1: stage quantized weights (coalesced; rows padded to 65 so
    //      eval s_w2[lane*65+i] hits bank (lane+i)&31 -> conflict-free).
#pragma unroll
    for (int r = 0; r < 16; ++r) {                 // 4096 w2 elements
        int idx = t + r * 256;
        s_mem[SW2_OFF + (idx >> 6) * 65 + (idx & 63)] = quant_fp4(w2[idx]);
    }
#pragma unroll
    for (int r = 0; r < 8; ++r) {                  // 2048 w3 elements
        int idx = t + r * 256;
        s_mem[SW3_OFF + (idx >> 6) * 65 + (idx & 63)] = quant_fp4(w3[idx]);
    }
    if (t < 64) s_mem[SW1_OFF + t] = quant_fp4(w1[t]);
    if (t < 32) s_mem[SW4_OFF + t] = quant_fp4(w4[t]);
    __syncthreads();

    int lane = t & 63;
    int w    = blockIdx.x * 4 + (t >> 6);          // wave id, 0..2047
    for (int p = w; p < N_PTS; p += COOP_WAVES) {  // wave-uniform trip count
        float x = fmaf((float)p, F_H, F_LO);

        // Layer 1: lane i holds h1_i
        float h1 = silu(fmaf(x, s_mem[SW1_OFF + lane], b1[lane]));

        // Layer 2: lane j accumulates over i (readlane broadcast of h1)
        float acc0 = b2[lane], acc1 = 0.0f;
#pragma unroll
        for (int i = 0; i < 64; i += 2) {
            acc0 = fmaf(rdlane(h1, i),     s_mem[SW2_OFF + lane * 65 + i],     acc0);
            acc1 = fmaf(rdlane(h1, i + 1), s_mem[SW2_OFF + lane * 65 + i + 1], acc1);
        }
        float h2 = silu(acc0 + acc1);

        // Layer 3: lane halves duplicate (same-address LDS = broadcast, free)
        int k = lane & 31;
        float a0 = b3[k], a1 = 0.0f;
#pragma unroll
        for (int i = 0; i < 64; i += 2) {
            a0 = fmaf(rdlane(h2, i),     s_mem[SW3_OFF + k * 65 + i],     a0);
            a1 = fmaf(rdlane(h2, i + 1), s_mem[SW3_OFF + k * 65 + i + 1], a1);
        }

        // Layer 4 + wave reduction (zero the duplicate half)
        float v = silu(a0 + a1) * s_mem[SW4_OFF + k];
        if (lane >= 32) v = 0.0f;
#pragma unroll
        for (int off = 32; off >= 1; off >>= 1) v += __shfl_xor(v, off, 64);
        if (lane == 0) table[p] = v + b4[0];
    }

    __threadfence();                               // device scope: cross-XCD
    grid.sync();

    // ---- Phase 2: lerp. Issue both sample loads BEFORE table staging so
    //      their HBM latency hides under the LDS fill.
    int gid = blockIdx.x * 256 + t;
    int n4  = n >> 2;
    int v0  = gid;
    int v1  = gid + COOP_BLOCKS * 256;
    float4 xv0 = make_float4(0.f, 0.f, 0.f, 0.f), xv1 = xv0;
    bool h0 = v0 < n4, h1v = v1 < n4;
    if (h0)  xv0 = ((const float4*)x_in)[v0];
    if (h1v) xv1 = ((const float4*)x_in)[v1];

    // Re-stage table into the same LDS (weights dead after grid.sync; the
    // grid.sync's block barrier makes the overwrite safe).
    float4* __restrict__ s4 = (float4*)s_mem;
    const float4* __restrict__ t4 = (const float4*)table;
    for (int i = t; i < (N_PTS + 3) / 4; i += 256) s4[i] = t4[i];
    __syncthreads();

    if (h0) {
        float4 ov;
        ov.x = lerp1(xv0.x, s_mem); ov.y = lerp1(xv0.y, s_mem);
        ov.z = lerp1(xv0.z, s_mem); ov.w = lerp1(xv0.w, s_mem);
        ((float4*)out)[v0] = ov;
    }
    if (h1v) {
        float4 ov;
        ov.x = lerp1(xv1.x, s_mem); ov.y = lerp1(xv1.y, s_mem);
        ov.z = lerp1(xv1.z, s_mem); ov.w = lerp1(xv1.w, s_mem);
        ((float4*)out)[v1] = ov;
    }
    // Spill for n4 > 2*grid and scalar tail (not hit at B=1M; safety only).
    for (int v = v1 + COOP_BLOCKS * 256; v < n4; v += COOP_BLOCKS * 256) {
        float4 xq = ((const float4*)x_in)[v];
        float4 ov;
        ov.x = lerp1(xq.x, s_mem); ov.y = lerp1(xq.y, s_mem);
        ov.z = lerp1(xq.z, s_mem); ov.w = lerp1(xq.w, s_mem);
        ((float4*)out)[v] = ov;
    }
    if (blockIdx.x == 0) {
        for (int i = (n & ~3) + t; i < n; i += 256)
            out[i] = lerp1(x_in[i], s_mem);
    }
}

// ======================= fallback path (R2, known-good) ====================
__global__ void quantize_kernel(const float* __restrict__ w1, const float* __restrict__ w2,
                                const float* __restrict__ w3, const float* __restrict__ w4,
                                float* __restrict__ qw) {
    int t = blockIdx.x * blockDim.x + threadIdx.x;
    if (t < 64)   qw[QW1_OFF + t] = quant_fp4(w1[t]);
    if (t < 4096) qw[QW2T_OFF + t] = quant_fp4(w2[(t & 63) * 64 + (t >> 6)]);
    if (t < 2048) qw[QW3T_OFF + t] = quant_fp4(w3[(t & 31) * 64 + (t >> 5)]);
    if (t < 32)   qw[QW4_OFF + t] = quant_fp4(w4[t]);
}

__global__ __launch_bounds__(256) void build_kernel(
        const float* __restrict__ qw,
        const float* __restrict__ b1, const float* __restrict__ b2,
        const float* __restrict__ b3, const float* __restrict__ b4,
        float* __restrict__ table) {
    int tid  = blockIdx.x * blockDim.x + threadIdx.x;
    int w    = tid >> 6;
    int lane = tid & 63;
    if (w >= N_PTS) return;
    const float* __restrict__ qw1  = qw + QW1_OFF;
    const float* __restrict__ qw2t = qw + QW2T_OFF;
    const float* __restrict__ qw3t = qw + QW3T_OFF;
    const float* __restrict__ qw4  = qw + QW4_OFF;
    float x = fmaf((float)w, F_H, F_LO);
    float h1 = silu(fmaf(x, qw1[lane], b1[lane]));
    float acc0 = b2[lane], acc1 = 0.0f;
#pragma unroll
    for (int i = 0; i < 64; i += 2) {
        acc0 = fmaf(rdlane(h1, i),     qw2t[i * 64 + lane],       acc0);
        acc1 = fmaf(rdlane(h1, i + 1), qw2t[(i + 1) * 64 + lane], acc1);
    }
    float h2 = silu(acc0 + acc1);
    int k = lane & 31;
    float a0 = b3[k], a1 = 0.0f;
#pragma unroll
    for (int i = 0; i < 64; i += 2) {
        a0 = fmaf(rdlane(h2, i),     qw3t[i * 32 + k],       a0);
        a1 = fmaf(rdlane(h2, i + 1), qw3t[(i + 1) * 32 + k], a1);
    }
    float v = silu(a0 + a1) * qw4[k];
    if (lane >= 32) v = 0.0f;
#pragma unroll
    for (int off = 32; off >= 1; off >>= 1) v += __shfl_xor(v, off, 64);
    if (lane == 0) table[w] = v + b4[0];
}

__global__ __launch_bounds__(256) void lerp_kernel(
        const float* __restrict__ x_in, const float* __restrict__ table,
        float* __restrict__ out, int n) {
    __shared__ float s_tab[4100];
    float4* __restrict__ s4 = (float4*)s_tab;
    const float4* __restrict__ t4 = (const float4*)table;
    for (int i = threadIdx.x; i < 1025; i += 256) s4[i] = t4[i];
    __syncthreads();
    int n4 = n >> 2;
    int stride = gridDim.x * blockDim.x;
    for (int v = blockIdx.x * blockDim.x + threadIdx.x; v < n4; v += stride) {
        float4 xv = ((const float4*)x_in)[v];
        float4 ov;
        ov.x = lerp1(xv.x, s_tab); ov.y = lerp1(xv.y, s_tab);
        ov.z = lerp1(xv.z, s_tab); ov.w = lerp1(xv.w, s_tab);
        ((float4*)out)[v] = ov;
    }
    if (blockIdx.x == 0) {
        for (int i = (n & ~3) + threadIdx.x; i < n; i += 256)
            out[i] = lerp1(x_in[i], s_tab);
    }
}

// ===========================================================================
extern "C" void kernel_launch(void* const* d_in, const int* in_sizes, int n_in,
                              void* d_out, int out_size, void* d_ws, size_t ws_size,
                              hipStream_t stream) {
    const float* x  = (const float*)d_in[0];
    const float* w1 = (const float*)d_in[1];
    const float* b1 = (const float*)d_in[2];
    const float* w2 = (const float*)d_in[3];
    const float* b2 = (const float*)d_in[4];
    const float* w3 = (const float*)d_in[5];
    const float* b3 = (const float*)d_in[6];
    const float* w4 = (const float*)d_in[7];
    const float* b4 = (const float*)d_in[8];
    float* out = (float*)d_out;
    float* qw  = (float*)d_ws;
    float* tab = qw + TAB_OFF;
    int n = in_sizes[0];

    void* args[] = { (void*)&x,
                     (void*)&w1, (void*)&b1, (void*)&w2, (void*)&b2,
                     (void*)&w3, (void*)&b3, (void*)&w4, (void*)&b4,
                     (void*)&tab, (void*)&out, (void*)&n };
    hipError_t err = hipLaunchCooperativeKernel((void*)fused_kernel,
                                                dim3(COOP_BLOCKS), dim3(256),
                                                args, 0, stream);
    if (err != hipSuccess) {
        (void)hipGetLastError();                   // clear sticky error
        hipLaunchKernelGGL(quantize_kernel, dim3(16), dim3(256), 0, stream,
                           w1, w2, w3, w4, qw);
        hipLaunchKernelGGL(build_kernel, dim3((N_PTS + 3) / 4), dim3(256), 0,
                           stream, qw, b1, b2, b3, b4, tab);
        int n4 = n >> 2;
        int grid = n4 > 0 ? ((n4 / 2 + 255) / 256) : 1;   // ~2 float4/thread
        if (grid < 1) grid = 1;
        hipLaunchKernelGGL(lerp_kernel, dim3(grid), dim3(256), 0, stream,
                           x, tab, out, n);
    }
}

// Round 6
// 80.368 us; speedup vs baseline: 1.9322x; 1.9322x over previous
//
#include <hip/hip_runtime.h>
#include <math.h>

// ---------------------------------------------------------------------------
// PolyNetFP4Sim: out = f(x), scalar->scalar 4-layer SiLU MLP (1->64->64->32->1)
// with fake-FP4 (1-2-1) weights. f tabulated on 4096 cells over [-6.75,6.75],
// then lerped (tails extrapolate linearly; silu is asymptotically linear).
// Round 6 (post coop-probe): grid.sync measured ~60us of stall -> back to two
// plain kernels (kernel boundary is cheap on this harness).
//   k1 build: 257 blocks x 1024 thr (16 waves) — weight LDS staging amortized
//             over 4x more waves than R3; one wave per table point.
//   k2 lerp:  NO LDS — table is L2/L3-hot (16KB); direct global gather kills
//             staging rounds, __syncthreads, and the 160k bank conflicts
//             measured in R5. Exactly one float4 per thread.
// ---------------------------------------------------------------------------

#define FAST_RCP(x) __builtin_amdgcn_rcpf(x)

#define N_CELLS 4096
#define N_PTS   (N_CELLS + 1)
#define F_LO    (-6.75f)
#define F_HI    (6.75f)
#define F_H     ((F_HI - F_LO) / (float)N_CELLS)
#define F_INVH  ((float)N_CELLS / (F_HI - F_LO))

// LDS layout for build (floats), rows padded to 65 -> conflict-free eval.
#define SW2_OFF 0                 /* 64 x 65 = 4160 */
#define SW3_OFF 4160              /* 32 x 65 = 2080 */
#define SW1_OFF 6240              /* 64 */
#define SW4_OFF 6304              /* 32 -> 6336 floats = 25.3 KB */
#define S_MEM_FLOATS 6336

__device__ __forceinline__ float quant_fp4(float w) {
    unsigned bits  = __float_as_uint(w);
    unsigned abits = bits & 0x7fffffffu;
    if (abits == 0u) return 0.0f;                  // ±0 -> 0
    int e  = (int)(abits >> 23) - 126;             // frexp: m in [0.5,1)
    int qe = e + 1;
    qe = qe < 0 ? 0 : (qe > 3 ? 3 : qe);
    float base  = (abits & 0x00400000u) ? 0.75f : 0.5f;   // m >= 0.75 ?
    float scale = (qe == 0) ? 0.5f : (qe == 1) ? 1.0f : (qe == 2) ? 2.0f : 4.0f;
    float val = base * scale;
    return (bits & 0x80000000u) ? -val : val;
}

__device__ __forceinline__ float silu(float a) {
    return a * FAST_RCP(1.0f + __expf(-a));
}

__device__ __forceinline__ float rdlane(float v, int i) {
    return __uint_as_float((unsigned)__builtin_amdgcn_readlane((int)__float_as_uint(v), i));
}

// One wave per table point; quantized weights staged once per 16-wave block.
__global__ __launch_bounds__(1024) void build_kernel(
        const float* __restrict__ w1, const float* __restrict__ b1,
        const float* __restrict__ w2, const float* __restrict__ b2,
        const float* __restrict__ w3, const float* __restrict__ b3,
        const float* __restrict__ w4, const float* __restrict__ b4,
        float* __restrict__ table) {
    __shared__ float s_mem[S_MEM_FLOATS];
    int t = threadIdx.x;

    // Stage quantized weights, coalesced (1024 threads: 4 rounds w2, 2 w3).
#pragma unroll
    for (int r = 0; r < 4; ++r) {
        int idx = t + r * 1024;
        s_mem[SW2_OFF + (idx >> 6) * 65 + (idx & 63)] = quant_fp4(w2[idx]);
    }
#pragma unroll
    for (int r = 0; r < 2; ++r) {
        int idx = t + r * 1024;
        s_mem[SW3_OFF + (idx >> 6) * 65 + (idx & 63)] = quant_fp4(w3[idx]);
    }
    if (t < 64) s_mem[SW1_OFF + t] = quant_fp4(w1[t]);
    if (t < 32) s_mem[SW4_OFF + t] = quant_fp4(w4[t]);
    __syncthreads();

    int lane = t & 63;
    int pt   = blockIdx.x * 16 + (t >> 6);         // one point per wave
    if (pt >= N_PTS) return;                       // wave-uniform exit
    float x = fmaf((float)pt, F_H, F_LO);

    // Layer 1: lane i holds h1_i
    float h1 = silu(fmaf(x, s_mem[SW1_OFF + lane], b1[lane]));

    // Layer 2: lane j accumulates over i (readlane broadcast of h1);
    // s_w2[lane*65+i] -> bank (lane+i)&31: conflict-free.
    float acc0 = b2[lane], acc1 = 0.0f;
#pragma unroll
    for (int i = 0; i < 64; i += 2) {
        acc0 = fmaf(rdlane(h1, i),     s_mem[SW2_OFF + lane * 65 + i],     acc0);
        acc1 = fmaf(rdlane(h1, i + 1), s_mem[SW2_OFF + lane * 65 + i + 1], acc1);
    }
    float h2 = silu(acc0 + acc1);

    // Layer 3: lane halves duplicate (same-address LDS = broadcast, free).
    int k = lane & 31;
    float a0 = b3[k], a1 = 0.0f;
#pragma unroll
    for (int i = 0; i < 64; i += 2) {
        a0 = fmaf(rdlane(h2, i),     s_mem[SW3_OFF + k * 65 + i],     a0);
        a1 = fmaf(rdlane(h2, i + 1), s_mem[SW3_OFF + k * 65 + i + 1], a1);
    }

    // Layer 4 + wave reduction (zero duplicate half).
    float v = silu(a0 + a1) * s_mem[SW4_OFF + k];
    if (lane >= 32) v = 0.0f;
#pragma unroll
    for (int off = 32; off >= 1; off >>= 1) v += __shfl_xor(v, off, 64);
    if (lane == 0) table[pt] = v + b4[0];
}

__device__ __forceinline__ float lerp1g(float xc, const float* __restrict__ tab) {
    float tt = fmaf(xc, F_INVH, 2048.0f);          // -F_LO*F_INVH == 2048 exact
    int i = (int)tt;
    i = i < 0 ? 0 : (i > N_CELLS - 1 ? N_CELLS - 1 : i);
    float fr = tt - (float)i;                      // <0 / >1 => extrapolation
    float f0 = tab[i];                             // L2/L3-hot gather
    float f1 = tab[i + 1];
    return fmaf(fr, f1 - f0, f0);
}

__global__ __launch_bounds__(256) void lerp_kernel(
        const float* __restrict__ x_in, const float* __restrict__ table,
        float* __restrict__ out, int n) {
    int gid = blockIdx.x * 256 + threadIdx.x;
    int n4  = n >> 2;
    if (gid < n4) {
        float4 xv = ((const float4*)x_in)[gid];
        float4 ov;
        ov.x = lerp1g(xv.x, table);
        ov.y = lerp1g(xv.y, table);
        ov.z = lerp1g(xv.z, table);
        ov.w = lerp1g(xv.w, table);
        ((float4*)out)[gid] = ov;
    }
    // Grid-stride spill + scalar tail (not hit at B=1M; safety only).
    for (int v = gid + (int)gridDim.x * 256; v < n4; v += (int)gridDim.x * 256) {
        float4 xv = ((const float4*)x_in)[v];
        float4 ov;
        ov.x = lerp1g(xv.x, table);
        ov.y = lerp1g(xv.y, table);
        ov.z = lerp1g(xv.z, table);
        ov.w = lerp1g(xv.w, table);
        ((float4*)out)[v] = ov;
    }
    if (blockIdx.x == 0) {
        for (int i = (n & ~3) + threadIdx.x; i < n; i += 256)
            out[i] = lerp1g(x_in[i], table);
    }
}

extern "C" void kernel_launch(void* const* d_in, const int* in_sizes, int n_in,
                              void* d_out, int out_size, void* d_ws, size_t ws_size,
                              hipStream_t stream) {
    const float* x  = (const float*)d_in[0];
    const float* w1 = (const float*)d_in[1];
    const float* b1 = (const float*)d_in[2];
    const float* w2 = (const float*)d_in[3];
    const float* b2 = (const float*)d_in[4];
    const float* w3 = (const float*)d_in[5];
    const float* b3 = (const float*)d_in[6];
    const float* w4 = (const float*)d_in[7];
    const float* b4 = (const float*)d_in[8];
    float* out = (float*)d_out;
    float* tab = (float*)d_ws;                     // 4097 floats = 16.4 KB
    int n = in_sizes[0];

    // 257 blocks x 16 waves: one wave per table point (4097 points).
    hipLaunchKernelGGL(build_kernel, dim3((N_PTS + 15) / 16), dim3(1024), 0,
                       stream, w1, b1, w2, b2, w3, b3, w4, b4, tab);
    // One float4 per thread.
    int n4 = n >> 2;
    int grid = n4 > 0 ? (n4 + 255) / 256 : 1;
    hipLaunchKernelGGL(lerp_kernel, dim3(grid), dim3(256), 0, stream,
                       x, tab, out, n);
}